// Round 14
// baseline (114.060 us; speedup 1.0000x reference)
//
#include <hip/hip_runtime.h>
#include <hip/hip_bf16.h>

// Problem constants
#define DD    256        // descriptor dim
#define KK    64         // clusters
#define NPIX  262144     // H*W
#define NW    128        // n-window
#define NWIN  8          // windows per block
#define GRID  256        // GRID * NWIN * NW == NPIX ; 1 block per CU
#define BLOCK 512        // 8 waves; x-tile lives in LDS -> phase B is LDS-only

// LDS strides (elements)
#define W_S   264        // W:   [64][264] bf16 (row 528 B, 16B-mult)
#define XT_S  132        // x_t: [256][132] bf16 (row 264 B, 8B-mult)
#define AB_S  136        // abar:[64][136] bf16 (row 272 B, 16B-mult)
#define XC_S  40         // slice rows: 40 shorts = 80 B
#define SV_S  257        // full-V staging stride (floats)

typedef __attribute__((ext_vector_type(8))) short bf16x8;
typedef __attribute__((ext_vector_type(4))) float f32x4;

union Frag { bf16x8 v; int i[4]; };

__device__ __forceinline__ int cvtpk(float a, float b) {
    // packed f32->bf16 RNE; lowers to v_cvt_pk_bf16_f32 on gfx950
    __hip_bfloat162 h = __float22bfloat162_rn(float2{a, b});
    int r; __builtin_memcpy(&r, &h, 4); return r;  // low short = a
}

// lgkm-only barrier: LDS visibility without draining in-flight global loads
__device__ __forceinline__ void lds_barrier() {
    asm volatile("s_waitcnt lgkmcnt(0)" ::: "memory");
    __builtin_amdgcn_s_barrier();
}

// waves_per_eu(2,2): 8 waves/CU = exactly 2/EU; pins the register budget to
// 256 so the ~145 live VGPRs never spill (R8: default heuristic snapped to 64
// and spilled 131 MB).
__global__ __attribute__((amdgpu_flat_work_group_size(BLOCK, BLOCK), amdgpu_waves_per_eu(2, 2)))
void netvlad_fused(const float* __restrict__ x, const float* __restrict__ conv_w,
                   const float* __restrict__ conv_b, float* __restrict__ Vpart,
                   float* __restrict__ asum_part)
{
    __shared__ short Wl[KK * W_S];              // 33792 B
    __shared__ short Ab[KK * AB_S];             // 17408 B
    __shared__ float asb[8][KK];                //  2048 B
    __shared__ short slice_mem[8 * 16 * XC_S];  // 10240 B: 8 wave-private 16x40 slices
    __shared__ union {
        short xt[DD * XT_S];                    // 67584 B: bf16 x-tile [d][n] for P2
        float sv[KK * SV_S];                    // 65792 B: epilogue staging (full V)
    } UX;
    // total 131072 B -> 1 block/CU

    const int t    = threadIdx.x;
    const int lane = t & 63;
    const int w    = t >> 6;        // wave 0..7
    const int l15  = lane & 15;
    const int q    = (lane >> 4) & 3;
    const int bid  = blockIdx.x;
    const size_t n0 = (size_t)bid * (NWIN * NW);

    // ---- P1 load mapping: wave-private 16 n-cols, chunks of 32 d ----
    const int p  = lane >> 2;            // 0..15 (d-pair)
    const int ng = lane & 3;             // 0..3  (4 n-cols each)
    const size_t nself0 = n0 + 16 * w + 4 * ng;   // window 0

    // prologue: window-0 chunks 0,1 in flight (depth-4 pipeline, slots 0,1)
    float4 pr[4][2];
    #pragma unroll
    for (int c = 0; c < 2; ++c)
        #pragma unroll
        for (int j = 0; j < 2; ++j)
            pr[c][j] = *(const float4*)(x + (size_t)(32 * c + 2 * p + j) * NPIX + nself0);
    __builtin_amdgcn_sched_barrier(0);   // pin

    // ---- stage W (fp32 -> bf16) into LDS, once ----
    #pragma unroll
    for (int i = 0; i < 32; ++i) {
        int idx = t + BLOCK * i;                 // 0..16383
        float wv = conv_w[idx];
        __hip_bfloat16 hb = __float2bfloat16(wv);
        short s; __builtin_memcpy(&s, &hb, 2);
        Wl[(idx >> 8) * W_S + (idx & 255)] = s;
    }

    // prologue: chunks 2,3 (slots 2,3)
    #pragma unroll
    for (int c = 2; c < 4; ++c)
        #pragma unroll
        for (int j = 0; j < 2; ++j)
            pr[c][j] = *(const float4*)(x + (size_t)(32 * c + 2 * p + j) * NPIX + nself0);
    __builtin_amdgcn_sched_barrier(0);   // pin

    float breg[4][4];
    #pragma unroll
    for (int mt = 0; mt < 4; ++mt)
        #pragma unroll
        for (int r = 0; r < 4; ++r)
            breg[mt][r] = conv_b[16 * mt + 4 * q + r];

    // persistent accumulators
    f32x4 acc[2][4];
    #pragma unroll
    for (int rg = 0; rg < 2; ++rg)
        #pragma unroll
        for (int ct = 0; ct < 4; ++ct)
            acc[rg][ct] = (f32x4){0.f, 0.f, 0.f, 0.f};
    float asumReg = 0.f;

    short* slice = &slice_mem[w * (16 * XC_S)];

    lds_barrier();   // W visible; pr loads stay in flight

    // ================= per-window: A (stage+logits) -> B (VLAD, LDS-only) =====
    for (int i = 0; i < NWIN; ++i) {
        const size_t nselfw = n0 + (size_t)i * NW + 16 * w + 4 * ng;

        f32x4 Lc[4];
        #pragma unroll
        for (int mt = 0; mt < 4; ++mt) Lc[mt] = (f32x4){0.f, 0.f, 0.f, 0.f};

        // ---- phase A: 8 chunks of 32 d ----
        #pragma unroll
        for (int ch = 0; ch < 8; ++ch) {
            const int cur = ch & 3;
            const float* r0 = (const float*)&pr[cur][0];   // x[d=32ch+2p  ][n..n+3]
            const float* r1 = (const float*)&pr[cur][1];   // x[d=32ch+2p+1][n..n+3]

            // stage -> wave-private slice ([n][d] for P1 B-frags), d-pair packing
            #pragma unroll
            for (int c = 0; c < 4; ++c) {
                int pk = cvtpk(r0[c], r1[c]);
                *(int*)&slice[(4 * ng + c) * XC_S + 2 * p] = pk;
            }
            // stage -> shared x-tile ([d][n] for P2 A-frags), n packing
            {
                int2 a; a.x = cvtpk(r0[0], r0[1]); a.y = cvtpk(r0[2], r0[3]);
                *(int2*)&UX.xt[(32 * ch + 2 * p) * XT_S + 16 * w + 4 * ng] = a;
                int2 b; b.x = cvtpk(r1[0], r1[1]); b.y = cvtpk(r1[2], r1[3]);
                *(int2*)&UX.xt[(32 * ch + 2 * p + 1) * XT_S + 16 * w + 4 * ng] = b;
            }

            // depth-4 prefetch: ch<4 -> this window's ch+4; ch>=4 -> next window's ch-4
            if (ch < 4) {
                #pragma unroll
                for (int j = 0; j < 2; ++j)
                    pr[cur][j] = *(const float4*)(x + (size_t)(32 * (ch + 4) + 2 * p + j) * NPIX + nselfw);
                __builtin_amdgcn_sched_barrier(0);   // pin
            } else if (i + 1 < NWIN) {
                #pragma unroll
                for (int j = 0; j < 2; ++j)
                    pr[cur][j] = *(const float4*)(x + (size_t)(32 * (ch - 4) + 2 * p + j) * NPIX + nselfw + NW);
                __builtin_amdgcn_sched_barrier(0);   // pin (stays in flight through phase B)
            }

            // P1 MFMA: logits += W[k][d-chunk] * x[d-chunk][n]
            Frag Bv = *(const Frag*)&slice[l15 * XC_S + 8 * q];
            #pragma unroll
            for (int mt = 0; mt < 4; ++mt) {
                Frag A = *(const Frag*)&Wl[(16 * mt + l15) * W_S + 32 * ch + 8 * q];
                Lc[mt] = __builtin_amdgcn_mfma_f32_16x16x32_bf16(A.v, Bv.v, Lc[mt], 0, 0, 0);
            }
        }

        // ---- softmax over k (in-register, wave-local) ----
        {
            float mx = -1e30f;
            #pragma unroll
            for (int mt = 0; mt < 4; ++mt)
                #pragma unroll
                for (int r = 0; r < 4; ++r) {
                    Lc[mt][r] += breg[mt][r];
                    mx = fmaxf(mx, Lc[mt][r]);
                }
            mx = fmaxf(mx, __shfl_xor(mx, 16));
            mx = fmaxf(mx, __shfl_xor(mx, 32));
            float s = 0.f;
            #pragma unroll
            for (int mt = 0; mt < 4; ++mt)
                #pragma unroll
                for (int r = 0; r < 4; ++r) {
                    float e = __expf(Lc[mt][r] - mx);
                    Lc[mt][r] = e;
                    s += e;
                }
            s += __shfl_xor(s, 16);
            s += __shfl_xor(s, 32);
            float inv = 1.0f / s;
            #pragma unroll
            for (int mt = 0; mt < 4; ++mt)
                #pragma unroll
                for (int r = 0; r < 4; ++r)
                    Lc[mt][r] *= inv;
        }

        // wave asum partial -> asb[w]
        #pragma unroll
        for (int mt = 0; mt < 4; ++mt)
            #pragma unroll
            for (int r = 0; r < 4; ++r) {
                float v = Lc[mt][r];
                v += __shfl_xor(v, 1);
                v += __shfl_xor(v, 2);
                v += __shfl_xor(v, 4);
                v += __shfl_xor(v, 8);
                if (l15 == 0) asb[w][16 * mt + 4 * q + r] = v;
            }

        // abar -> Ab (bf16), wave-private 16 columns
        #pragma unroll
        for (int mt = 0; mt < 4; ++mt)
            #pragma unroll
            for (int r = 0; r < 4; ++r) {
                __hip_bfloat16 hb = __float2bfloat16(Lc[mt][r]);
                short sv_; __builtin_memcpy(&sv_, &hb, 2);
                Ab[(16 * mt + 4 * q + r) * AB_S + 16 * w + l15] = sv_;
            }

        lds_barrier();   // xt, Ab, asb published; prefetched globals stay in flight

        // asum gather (once per window)
        if (t < KK) {
            float s = 0.f;
            #pragma unroll
            for (int ww = 0; ww < 8; ++ww) s += asb[ww][t];
            asumReg += s;
        }

        // ---- phase B: VLAD GEMM, 100% LDS (no vmcnt waits) ----
        // wave w owns d-tiles 2w, 2w+1: A-frag rows d = 32w + 16rg + l15
        #pragma unroll
        for (int s = 0; s < 4; ++s) {
            Frag Af0 = *(const Frag*)&UX.xt[(32 * w + l15) * XT_S + 32 * s + 8 * q];
            Frag Af1 = *(const Frag*)&UX.xt[(32 * w + 16 + l15) * XT_S + 32 * s + 8 * q];
            Frag Bf[4];
            #pragma unroll
            for (int ct = 0; ct < 4; ++ct)
                Bf[ct] = *(const Frag*)&Ab[(16 * ct + l15) * AB_S + 32 * s + 8 * q];
            #pragma unroll
            for (int ct = 0; ct < 4; ++ct) {
                acc[0][ct] = __builtin_amdgcn_mfma_f32_16x16x32_bf16(Af0.v, Bf[ct].v, acc[0][ct], 0, 0, 0);
                acc[1][ct] = __builtin_amdgcn_mfma_f32_16x16x32_bf16(Af1.v, Bf[ct].v, acc[1][ct], 0, 0, 0);
            }
        }

        lds_barrier();   // all waves done reading xt/Ab -> next window may overwrite
    }

    // ---- epilogue: asum + full V -> LDS -> plain coalesced stores ----
    if (t < KK) asum_part[(size_t)bid * KK + t] = asumReg;

    // acc element (rg, ct, r): k = 16ct + l15, d = 32w + 16rg + 4q + r
    #pragma unroll
    for (int rg = 0; rg < 2; ++rg)
        #pragma unroll
        for (int ct = 0; ct < 4; ++ct)
            #pragma unroll
            for (int r = 0; r < 4; ++r) {
                int k = 16 * ct + l15;
                int d = 32 * w + 16 * rg + 4 * q + r;
                UX.sv[k * SV_S + d] = acc[rg][ct][r];
            }
    __syncthreads();

    float* vout = Vpart + (size_t)bid * (KK * DD);
    #pragma unroll
    for (int ii = 0; ii < 32; ++ii) {
        int idx = t + BLOCK * ii;       // 0..16383
        vout[idx] = UX.sv[(idx >> 8) * SV_S + (idx & 255)];
    }
}

// Merged reduce + finalize: 256 blocks reduce Vpart; last-done block (device-
// scope atomic ticket, rocPRIM pattern) reduces asum and runs finalize inline.
// Saves one kernel launch + one full pass over Vred.
__global__ __launch_bounds__(256)
void netvlad_reduce_finalize(const float* __restrict__ Vpart, const float* __restrict__ asum_part,
                             float* __restrict__ Vred, const float* __restrict__ c,
                             float* __restrict__ y, unsigned int* __restrict__ done)
{
    __shared__ float sbuf[256];
    const int t = threadIdx.x;

    // ---- per-block V reduction: 64 outputs ----
    const int o = blockIdx.x * 64 + (t & 63);
    const int g = t >> 6;
    float s = 0.f;
    #pragma unroll 8
    for (int i = 0; i < 64; ++i)
        s += Vpart[(size_t)(g * 64 + i) * (KK * DD) + o];
    sbuf[t] = s;
    __syncthreads();
    if (t < 64) Vred[o] = sbuf[t] + sbuf[t + 64] + sbuf[t + 128] + sbuf[t + 192];

    // ---- last-block ticket (device scope: fence + default-device atomicAdd) ----
    __shared__ unsigned int lastFlag;
    __threadfence();   // release our Vred writes to device scope
    if (t == 0) lastFlag = (atomicAdd(done, 1u) == (GRID - 1));
    __syncthreads();
    if (!lastFlag) return;
    __threadfence();   // acquire all other blocks' Vred writes

    // ---- asum reduce (tiny) ----
    __shared__ float sa[KK];
    if (t < KK) {
        float a = 0.f;
        for (int i = 0; i < GRID; ++i) a += asum_part[(size_t)i * KK + t];
        sa[t] = a;
    }

    // ---- finalize (256 threads) ----
    __shared__ float sV[KK * DD];    // 65536 B
    __shared__ float colf[DD];
    __shared__ float rowf[KK];
    __syncthreads();

    #pragma unroll 8
    for (int i = 0; i < 64; ++i) {
        int idx = t + 256 * i;
        sV[idx] = Vred[idx] - c[idx] * sa[idx >> 8];
    }
    __syncthreads();

    {   // column (d) norms over k: t = d
        float ss = 0.f;
        for (int k = 0; k < KK; ++k) { float v = sV[k * DD + t]; ss += v * v; }
        colf[t] = 1.0f / fmaxf(sqrtf(ss), 1e-12f);
    }
    __syncthreads();

    #pragma unroll 8
    for (int i = 0; i < 64; ++i) {
        int idx = t + 256 * i;
        sV[idx] *= colf[idx & 255];
    }
    __syncthreads();

    if (t < KK) {   // row (k) norms over d
        float ss = 0.f;
        for (int j = 0; j < DD; ++j) { float v = sV[t * DD + j]; ss += v * v; }
        rowf[t] = 1.0f / fmaxf(sqrtf(ss), 1e-12f);
    }
    __syncthreads();

    #pragma unroll 8
    for (int i = 0; i < 64; ++i) {
        int idx = t + 256 * i;
        y[idx] = sV[idx] * rowf[idx >> 8];
    }
}

extern "C" void kernel_launch(void* const* d_in, const int* in_sizes, int n_in,
                              void* d_out, int out_size, void* d_ws, size_t ws_size,
                              hipStream_t stream) {
    const float* x      = (const float*)d_in[0];
    const float* c      = (const float*)d_in[1];
    const float* conv_w = (const float*)d_in[2];
    const float* conv_b = (const float*)d_in[3];
    float* y = (float*)d_out;

    // workspace: 256*16384 + 256*64 + 16384 floats + 1 uint (~16.9 MB)
    float* Vpart     = (float*)d_ws;
    float* asum_part = Vpart + (size_t)GRID * KK * DD;
    float* Vred      = asum_part + (size_t)GRID * KK;
    unsigned int* done = (unsigned int*)(Vred + KK * DD);

    // only the 4-byte ticket counter needs clearing (workspace is poisoned)
    hipMemsetAsync(done, 0, sizeof(unsigned int), stream);
    netvlad_fused<<<GRID, BLOCK, 0, stream>>>(x, conv_w, conv_b, Vpart, asum_part);
    netvlad_reduce_finalize<<<GRID, 256, 0, stream>>>(Vpart, asum_part, Vred, c, y, done);
}

// Round 15
// 84.644 us; speedup vs baseline: 1.3475x; 1.3475x over previous
//
#include <hip/hip_runtime.h>
#include <hip/hip_bf16.h>

// Problem constants
#define DD    256        // descriptor dim
#define KK    64         // clusters
#define NPIX  262144     // H*W
#define NW    128        // n-window
#define NWIN  8          // windows per block
#define GRID  256        // GRID * NWIN * NW == NPIX ; 1 block per CU
#define BLOCK 512        // 8 waves; x-tile lives in LDS -> phase B is LDS-only

// LDS strides (elements)
#define W_S   264        // W:   [64][264] bf16 (row 528 B, 16B-mult)
#define XT_S  132        // x_t: [256][132] bf16 (row 264 B, 8B-mult)
#define AB_S  136        // abar:[64][136] bf16 (row 272 B, 16B-mult)
#define XC_S  40         // slice rows: 40 shorts = 80 B
#define SV_S  257        // full-V staging stride (floats)

typedef __attribute__((ext_vector_type(8))) short bf16x8;
typedef __attribute__((ext_vector_type(4))) float f32x4;

union Frag { bf16x8 v; int i[4]; };

__device__ __forceinline__ int cvtpk(float a, float b) {
    // packed f32->bf16 RNE; lowers to v_cvt_pk_bf16_f32 on gfx950
    __hip_bfloat162 h = __float22bfloat162_rn(float2{a, b});
    int r; __builtin_memcpy(&r, &h, 4); return r;  // low short = a
}

// lgkm-only barrier: LDS visibility without draining in-flight global loads
__device__ __forceinline__ void lds_barrier() {
    asm volatile("s_waitcnt lgkmcnt(0)" ::: "memory");
    __builtin_amdgcn_s_barrier();
}

// waves_per_eu(2,2): 8 waves/CU = exactly 2/EU; pins the register budget to
// 256 so the ~145 live VGPRs never spill (R8: default heuristic snapped to 64
// and spilled 131 MB).
__global__ __attribute__((amdgpu_flat_work_group_size(BLOCK, BLOCK), amdgpu_waves_per_eu(2, 2)))
void netvlad_fused(const float* __restrict__ x, const float* __restrict__ conv_w,
                   const float* __restrict__ conv_b, float* __restrict__ Vpart,
                   float* __restrict__ asum_part)
{
    __shared__ short Wl[KK * W_S];              // 33792 B
    __shared__ short Ab[KK * AB_S];             // 17408 B
    __shared__ float asb[8][KK];                //  2048 B
    __shared__ short slice_mem[8 * 16 * XC_S];  // 10240 B: 8 wave-private 16x40 slices
    __shared__ union {
        short xt[DD * XT_S];                    // 67584 B: bf16 x-tile [d][n] for P2
        float sv[KK * SV_S];                    // 65792 B: epilogue staging (full V)
    } UX;
    // total 131072 B -> 1 block/CU

    const int t    = threadIdx.x;
    const int lane = t & 63;
    const int w    = t >> 6;        // wave 0..7
    const int l15  = lane & 15;
    const int q    = (lane >> 4) & 3;
    const int bid  = blockIdx.x;
    const size_t n0 = (size_t)bid * (NWIN * NW);

    // ---- P1 load mapping: wave-private 16 n-cols, chunks of 32 d ----
    const int p  = lane >> 2;            // 0..15 (d-pair)
    const int ng = lane & 3;             // 0..3  (4 n-cols each)
    const size_t nself0 = n0 + 16 * w + 4 * ng;   // window 0

    // prologue: window-0 chunks 0,1 in flight (depth-4 pipeline, slots 0,1)
    float4 pr[4][2];
    #pragma unroll
    for (int c = 0; c < 2; ++c)
        #pragma unroll
        for (int j = 0; j < 2; ++j)
            pr[c][j] = *(const float4*)(x + (size_t)(32 * c + 2 * p + j) * NPIX + nself0);
    __builtin_amdgcn_sched_barrier(0);   // pin

    // ---- stage W (fp32 -> bf16) into LDS, once ----
    #pragma unroll
    for (int i = 0; i < 32; ++i) {
        int idx = t + BLOCK * i;                 // 0..16383
        float wv = conv_w[idx];
        __hip_bfloat16 hb = __float2bfloat16(wv);
        short s; __builtin_memcpy(&s, &hb, 2);
        Wl[(idx >> 8) * W_S + (idx & 255)] = s;
    }

    // prologue: chunks 2,3 (slots 2,3)
    #pragma unroll
    for (int c = 2; c < 4; ++c)
        #pragma unroll
        for (int j = 0; j < 2; ++j)
            pr[c][j] = *(const float4*)(x + (size_t)(32 * c + 2 * p + j) * NPIX + nself0);
    __builtin_amdgcn_sched_barrier(0);   // pin

    float breg[4][4];
    #pragma unroll
    for (int mt = 0; mt < 4; ++mt)
        #pragma unroll
        for (int r = 0; r < 4; ++r)
            breg[mt][r] = conv_b[16 * mt + 4 * q + r];

    // persistent accumulators
    f32x4 acc[2][4];
    #pragma unroll
    for (int rg = 0; rg < 2; ++rg)
        #pragma unroll
        for (int ct = 0; ct < 4; ++ct)
            acc[rg][ct] = (f32x4){0.f, 0.f, 0.f, 0.f};
    float asumReg = 0.f;

    short* slice = &slice_mem[w * (16 * XC_S)];

    lds_barrier();   // W visible; pr loads stay in flight

    // ================= per-window: A (stage+logits) -> B (VLAD, LDS-only) =====
    for (int i = 0; i < NWIN; ++i) {
        const size_t nselfw = n0 + (size_t)i * NW + 16 * w + 4 * ng;

        f32x4 Lc[4];
        #pragma unroll
        for (int mt = 0; mt < 4; ++mt) Lc[mt] = (f32x4){0.f, 0.f, 0.f, 0.f};

        // ---- phase A: 8 chunks of 32 d ----
        #pragma unroll
        for (int ch = 0; ch < 8; ++ch) {
            const int cur = ch & 3;
            const float* r0 = (const float*)&pr[cur][0];   // x[d=32ch+2p  ][n..n+3]
            const float* r1 = (const float*)&pr[cur][1];   // x[d=32ch+2p+1][n..n+3]

            // stage -> wave-private slice ([n][d] for P1 B-frags), d-pair packing
            #pragma unroll
            for (int c = 0; c < 4; ++c) {
                int pk = cvtpk(r0[c], r1[c]);
                *(int*)&slice[(4 * ng + c) * XC_S + 2 * p] = pk;
            }
            // stage -> shared x-tile ([d][n] for P2 A-frags), n packing
            {
                int2 a; a.x = cvtpk(r0[0], r0[1]); a.y = cvtpk(r0[2], r0[3]);
                *(int2*)&UX.xt[(32 * ch + 2 * p) * XT_S + 16 * w + 4 * ng] = a;
                int2 b; b.x = cvtpk(r1[0], r1[1]); b.y = cvtpk(r1[2], r1[3]);
                *(int2*)&UX.xt[(32 * ch + 2 * p + 1) * XT_S + 16 * w + 4 * ng] = b;
            }

            // depth-4 prefetch: ch<4 -> this window's ch+4; ch>=4 -> next window's ch-4
            if (ch < 4) {
                #pragma unroll
                for (int j = 0; j < 2; ++j)
                    pr[cur][j] = *(const float4*)(x + (size_t)(32 * (ch + 4) + 2 * p + j) * NPIX + nselfw);
                __builtin_amdgcn_sched_barrier(0);   // pin
            } else if (i + 1 < NWIN) {
                #pragma unroll
                for (int j = 0; j < 2; ++j)
                    pr[cur][j] = *(const float4*)(x + (size_t)(32 * (ch - 4) + 2 * p + j) * NPIX + nselfw + NW);
                __builtin_amdgcn_sched_barrier(0);   // pin (stays in flight through phase B)
            }

            // P1 MFMA: logits += W[k][d-chunk] * x[d-chunk][n]
            Frag Bv = *(const Frag*)&slice[l15 * XC_S + 8 * q];
            #pragma unroll
            for (int mt = 0; mt < 4; ++mt) {
                Frag A = *(const Frag*)&Wl[(16 * mt + l15) * W_S + 32 * ch + 8 * q];
                Lc[mt] = __builtin_amdgcn_mfma_f32_16x16x32_bf16(A.v, Bv.v, Lc[mt], 0, 0, 0);
            }
        }

        // ---- softmax over k (in-register, wave-local) ----
        {
            float mx = -1e30f;
            #pragma unroll
            for (int mt = 0; mt < 4; ++mt)
                #pragma unroll
                for (int r = 0; r < 4; ++r) {
                    Lc[mt][r] += breg[mt][r];
                    mx = fmaxf(mx, Lc[mt][r]);
                }
            mx = fmaxf(mx, __shfl_xor(mx, 16));
            mx = fmaxf(mx, __shfl_xor(mx, 32));
            float s = 0.f;
            #pragma unroll
            for (int mt = 0; mt < 4; ++mt)
                #pragma unroll
                for (int r = 0; r < 4; ++r) {
                    float e = __expf(Lc[mt][r] - mx);
                    Lc[mt][r] = e;
                    s += e;
                }
            s += __shfl_xor(s, 16);
            s += __shfl_xor(s, 32);
            float inv = 1.0f / s;
            #pragma unroll
            for (int mt = 0; mt < 4; ++mt)
                #pragma unroll
                for (int r = 0; r < 4; ++r)
                    Lc[mt][r] *= inv;
        }

        // wave asum partial -> asb[w]
        #pragma unroll
        for (int mt = 0; mt < 4; ++mt)
            #pragma unroll
            for (int r = 0; r < 4; ++r) {
                float v = Lc[mt][r];
                v += __shfl_xor(v, 1);
                v += __shfl_xor(v, 2);
                v += __shfl_xor(v, 4);
                v += __shfl_xor(v, 8);
                if (l15 == 0) asb[w][16 * mt + 4 * q + r] = v;
            }

        // abar -> Ab (bf16), wave-private 16 columns
        #pragma unroll
        for (int mt = 0; mt < 4; ++mt)
            #pragma unroll
            for (int r = 0; r < 4; ++r) {
                __hip_bfloat16 hb = __float2bfloat16(Lc[mt][r]);
                short sv_; __builtin_memcpy(&sv_, &hb, 2);
                Ab[(16 * mt + 4 * q + r) * AB_S + 16 * w + l15] = sv_;
            }

        lds_barrier();   // xt, Ab, asb published; prefetched globals stay in flight

        // asum gather (once per window)
        if (t < KK) {
            float s = 0.f;
            #pragma unroll
            for (int ww = 0; ww < 8; ++ww) s += asb[ww][t];
            asumReg += s;
        }

        // ---- phase B: VLAD GEMM, 100% LDS (no vmcnt waits) ----
        // wave w owns d-tiles 2w, 2w+1: A-frag rows d = 32w + 16rg + l15
        #pragma unroll
        for (int s = 0; s < 4; ++s) {
            Frag Af0 = *(const Frag*)&UX.xt[(32 * w + l15) * XT_S + 32 * s + 8 * q];
            Frag Af1 = *(const Frag*)&UX.xt[(32 * w + 16 + l15) * XT_S + 32 * s + 8 * q];
            Frag Bf[4];
            #pragma unroll
            for (int ct = 0; ct < 4; ++ct)
                Bf[ct] = *(const Frag*)&Ab[(16 * ct + l15) * AB_S + 32 * s + 8 * q];
            #pragma unroll
            for (int ct = 0; ct < 4; ++ct) {
                acc[0][ct] = __builtin_amdgcn_mfma_f32_16x16x32_bf16(Af0.v, Bf[ct].v, acc[0][ct], 0, 0, 0);
                acc[1][ct] = __builtin_amdgcn_mfma_f32_16x16x32_bf16(Af1.v, Bf[ct].v, acc[1][ct], 0, 0, 0);
            }
        }

        lds_barrier();   // all waves done reading xt/Ab -> next window may overwrite
    }

    // ---- epilogue: asum + full V -> LDS -> plain coalesced stores ----
    if (t < KK) asum_part[(size_t)bid * KK + t] = asumReg;

    // acc element (rg, ct, r): k = 16ct + l15, d = 32w + 16rg + 4q + r
    #pragma unroll
    for (int rg = 0; rg < 2; ++rg)
        #pragma unroll
        for (int ct = 0; ct < 4; ++ct)
            #pragma unroll
            for (int r = 0; r < 4; ++r) {
                int k = 16 * ct + l15;
                int d = 32 * w + 16 * rg + 4 * q + r;
                UX.sv[k * SV_S + d] = acc[rg][ct][r];
            }
    __syncthreads();

    float* vout = Vpart + (size_t)bid * (KK * DD);
    #pragma unroll
    for (int ii = 0; ii < 32; ++ii) {
        int idx = t + BLOCK * ii;       // 0..16383
        vout[idx] = UX.sv[(idx >> 8) * SV_S + (idx & 255)];
    }
}

__global__ __launch_bounds__(256)
void netvlad_reduce(const float* __restrict__ Vpart, const float* __restrict__ asum_part,
                    float* __restrict__ Vred, float* __restrict__ asum_red)
{
    __shared__ float sbuf[256];
    const int t = threadIdx.x;
    if (blockIdx.x < 256) {
        const int o = blockIdx.x * 64 + (t & 63);
        const int g = t >> 6;
        float s = 0.f;
        #pragma unroll 8
        for (int i = 0; i < 64; ++i)
            s += Vpart[(size_t)(g * 64 + i) * (KK * DD) + o];
        sbuf[t] = s;
        __syncthreads();
        if (t < 64) Vred[o] = sbuf[t] + sbuf[t + 64] + sbuf[t + 128] + sbuf[t + 192];
    } else {
        const int k = t & 63;
        const int g = t >> 6;
        float s = 0.f;
        #pragma unroll 8
        for (int i = 0; i < 64; ++i)
            s += asum_part[(size_t)(g * 64 + i) * KK + k];
        sbuf[t] = s;
        __syncthreads();
        if (t < 64) asum_red[k] = sbuf[t] + sbuf[t + 64] + sbuf[t + 128] + sbuf[t + 192];
    }
}

__global__ __launch_bounds__(1024)
void netvlad_finalize(const float* __restrict__ Vws, const float* __restrict__ asum_ws,
                      const float* __restrict__ c, float* __restrict__ y)
{
    __shared__ float sV[KK * DD];
    __shared__ float sa[KK];
    __shared__ float colf[DD];
    __shared__ float rowf[KK];
    const int t = threadIdx.x;

    if (t < KK) sa[t] = asum_ws[t];
    __syncthreads();

    #pragma unroll
    for (int i = 0; i < 16; ++i) {
        int idx = t + 1024 * i;
        sV[idx] = Vws[idx] - c[idx] * sa[idx >> 8];
    }
    __syncthreads();

    if (t < DD) {   // column (d) norms over k
        float s = 0.f;
        for (int k = 0; k < KK; ++k) { float v = sV[k * DD + t]; s += v * v; }
        colf[t] = 1.0f / fmaxf(sqrtf(s), 1e-12f);
    }
    __syncthreads();

    #pragma unroll
    for (int i = 0; i < 16; ++i) {
        int idx = t + 1024 * i;
        sV[idx] *= colf[idx & 255];
    }
    __syncthreads();

    {   // row (k) norms over d: 16 threads per row
        int k = t >> 4, p = t & 15;
        float s = 0.f;
        #pragma unroll
        for (int j = 0; j < 16; ++j) { float v = sV[k * DD + p + 16 * j]; s += v * v; }
        s += __shfl_xor(s, 1);
        s += __shfl_xor(s, 2);
        s += __shfl_xor(s, 4);
        s += __shfl_xor(s, 8);
        if (p == 0) rowf[k] = 1.0f / fmaxf(sqrtf(s), 1e-12f);
    }
    __syncthreads();

    #pragma unroll
    for (int i = 0; i < 16; ++i) {
        int idx = t + 1024 * i;
        y[idx] = sV[idx] * rowf[idx >> 8];
    }
}

extern "C" void kernel_launch(void* const* d_in, const int* in_sizes, int n_in,
                              void* d_out, int out_size, void* d_ws, size_t ws_size,
                              hipStream_t stream) {
    const float* x      = (const float*)d_in[0];
    const float* c      = (const float*)d_in[1];
    const float* conv_w = (const float*)d_in[2];
    const float* conv_b = (const float*)d_in[3];
    float* y = (float*)d_out;

    // workspace: 256*16384 + 256*64 + 16384 + 64 floats (~16.9 MB)
    float* Vpart     = (float*)d_ws;
    float* asum_part = Vpart + (size_t)GRID * KK * DD;
    float* Vred      = asum_part + (size_t)GRID * KK;
    float* asum_red  = Vred + KK * DD;

    // no memset needed: all partials are fully overwritten with plain stores
    netvlad_fused<<<GRID, BLOCK, 0, stream>>>(x, conv_w, conv_b, Vpart, asum_part);
    netvlad_reduce<<<257, 256, 0, stream>>>(Vpart, asum_part, Vred, asum_red);
    netvlad_finalize<<<1, 1024, 0, stream>>>(Vred, asum_red, c, y);
}